// Round 17
// baseline (291.858 us; speedup 1.0000x reference)
//
#include <hip/hip_runtime.h>
#include <hip/hip_bf16.h>

// GATModel: 3-layer GAT (heads 4/4/1) + BN/ELU + residual + mean-pool + conv1d head.
// N=50000 nodes, E=800000 edges (+N self-loops handled analytically).
//
// R16 changes vs R15-best (273.8us; fill_csr surfaced at 56us: WRITE_SIZE
// 52.7MB for 3.2MB of csr = 16x write-amplification from scattered 4B stores
// (per-XCD line RFO + multi-XCD writeback), plus atomic-return -> store chains):
//  - fill_csr: non-temporal scatter stores (no line allocation/RFO) and
//    2 edges/thread (grid 1563 blocks -> ~24 waves/CU of atomic MLP).
//  - everything else unchanged (R12-best agg, R15 head, MFMA gemms).
//
// Workspace (~58.5 MB): see offsets in kernel_launch.

#define NNODES 50000
#define NEDGES 800000
#define BN_INV 0.9999950000374997f  // 1/sqrt(1+1e-5)
#define SCAN_NB 49                  // ceil(NNODES/1024)

typedef __attribute__((ext_vector_type(8))) short bf16x8;
typedef __attribute__((ext_vector_type(4))) float f32x4;
typedef __attribute__((ext_vector_type(2))) float f32x2;

__device__ __forceinline__ unsigned bf16rne(float f) {   // fp32 -> bf16 bits (RNE)
  unsigned u = __float_as_uint(f);
  return (u + 0x7fffu + ((u >> 16) & 1u)) >> 16;
}

__device__ __forceinline__ unsigned char fp8enc(float f) {  // fp32 -> OCP e4m3 (HW RNE/sat)
  return (unsigned char)(__builtin_amdgcn_cvt_pk_fp8_f32(f, f, 0u, false) & 0xffu);
}

// ---------------- CSR build ----------------

__global__ __launch_bounds__(256) void count_deg(const int* __restrict__ dst,
                                                 int* __restrict__ deg, int E4) {
  int i = blockIdx.x * 256 + threadIdx.x;
  if (i < E4) {
    int4 d = *(const int4*)&dst[i * 4];
    atomicAdd(&deg[d.x], 1);
    atomicAdd(&deg[d.y], 1);
    atomicAdd(&deg[d.z], 1);
    atomicAdd(&deg[d.w], 1);
  }
}

// block-local exclusive scan: loc[i] = prefix within block, bsum[b] = block total
__global__ __launch_bounds__(1024) void scan_local(const int* __restrict__ deg,
    int* __restrict__ loc, int* __restrict__ bsum, int Nn) {
  __shared__ int wsum[16];
  __shared__ int woff[17];
  int b = blockIdx.x, t = threadIdx.x, lane = t & 63, w = t >> 6;
  int i = b * 1024 + t;
  int v = (i < Nn) ? deg[i] : 0;
  int incl = v;
#pragma unroll
  for (int o = 1; o < 64; o <<= 1) { int x = __shfl_up(incl, o); if (lane >= o) incl += x; }
  if (lane == 63) wsum[w] = incl;
  __syncthreads();
  if (t == 0) {
    int r = 0;
#pragma unroll
    for (int j = 0; j < 16; ++j) { woff[j] = r; r += wsum[j]; }
    bsum[b] = r;
  }
  __syncthreads();
  if (i < Nn) loc[i] = woff[w] + incl - v;
}

// add scanned block bases; emit offs + cursor; offs[Nn] = total
__global__ __launch_bounds__(1024) void scan_finish(const int* __restrict__ loc,
    const int* __restrict__ bsum, int* __restrict__ offs, int* __restrict__ cursor,
    int Nn, int nb) {
  __shared__ int boff[65];
  int b = blockIdx.x, t = threadIdx.x;
  if (t < 64) {
    int v = (t < nb) ? bsum[t] : 0;
    int incl = v;
#pragma unroll
    for (int o = 1; o < 64; o <<= 1) { int x = __shfl_up(incl, o); if (t >= o) incl += x; }
    boff[t + 1] = incl;
    if (t == 0) boff[0] = 0;
  }
  __syncthreads();
  int base = boff[b];
  int i = b * 1024 + t;
  if (i < Nn) { int o = loc[i] + base; offs[i] = o; cursor[i] = o; }
  if (b == 0 && t == 0) offs[Nn] = boff[nb];
}

// 2 edges/thread; nt scatter stores (no line RFO / write-allocate)
__global__ __launch_bounds__(256) void fill_csr(const int* __restrict__ src,
    const int* __restrict__ dst, int* __restrict__ cursor,
    int* __restrict__ csr, int E2) {
  int i = blockIdx.x * 256 + threadIdx.x;
  if (i < E2) {
    int2 s = *(const int2*)&src[i * 2];
    int2 d = *(const int2*)&dst[i * 2];
    int p0 = atomicAdd(&cursor[d.x], 1);
    int p1 = atomicAdd(&cursor[d.y], 1);
    __builtin_nontemporal_store(s.x, &csr[p0]);
    __builtin_nontemporal_store(s.y, &csr[p1]);
  }
}

// --------- prep: W0t/W1t/W2t (bf16, transposed) + u = W @ a_{s,d} vectors --------

__global__ __launch_bounds__(256) void prep_kernel(
    const float* __restrict__ W0, const float* __restrict__ W1, const float* __restrict__ W2,
    const float* __restrict__ a0s, const float* __restrict__ a0d,
    const float* __restrict__ a1s, const float* __restrict__ a1d,
    const float* __restrict__ a2s, const float* __restrict__ a2d,
    unsigned short* __restrict__ W0t, unsigned short* __restrict__ W1t,
    unsigned short* __restrict__ W2t,
    float* __restrict__ u0s, float* __restrict__ u0d,
    float* __restrict__ u1s, float* __restrict__ u1d,
    float* __restrict__ u2s, float* __restrict__ u2d) {
  int b = blockIdx.x, t = threadIdx.x;
  if (b < 64) {                       // W0t
    int idx = b * 256 + t; int c = idx >> 7, k = idx & 127;
    W0t[idx] = (unsigned short)bf16rne(W0[k * 128 + c]);
  } else if (b < 128) {               // W1t
    int idx = (b - 64) * 256 + t; int c = idx >> 7, k = idx & 127;
    W1t[idx] = (unsigned short)bf16rne(W1[k * 128 + c]);
  } else if (b < 144) {               // W2t (32 x 128)
    int idx = (b - 128) * 256 + t; int c = idx >> 7, k = idx & 127;
    W2t[idx] = (unsigned short)bf16rne(W2[k * 32 + c]);
  } else if (b == 144) {              // u0
    for (int it = 0; it < 4; ++it) {
      int idx = it * 256 + t;         // 0..1023
      int k = idx >> 3, rem = idx & 7, h = rem >> 1, sd = rem & 1;
      const float* av = sd ? a0d : a0s;
      float s = 0.f;
      for (int o = 0; o < 32; ++o) s += W0[k * 128 + h * 32 + o] * av[h * 32 + o];
      (sd ? u0d : u0s)[k * 4 + h] = s;
    }
  } else if (b == 145) {              // u1
    for (int it = 0; it < 4; ++it) {
      int idx = it * 256 + t;
      int k = idx >> 3, rem = idx & 7, h = rem >> 1, sd = rem & 1;
      const float* av = sd ? a1d : a1s;
      float s = 0.f;
      for (int o = 0; o < 32; ++o) s += W1[k * 128 + h * 32 + o] * av[h * 32 + o];
      (sd ? u1d : u1s)[k * 4 + h] = s;
    }
  } else {                            // u2 (256 outputs)
    int k = t >> 1, sd = t & 1;
    const float* av = sd ? a2d : a2s;
    float s = 0.f;
    for (int o = 0; o < 32; ++o) s += W2[k * 32 + o] * av[o];
    (sd ? u2d : u2s)[k] = s;
  }
}

// --------- xprep: x(f32) -> xbf(bf16) + es0/ed0 = x . u0 (one wave per node) -----

__global__ __launch_bounds__(256) void xprep_kernel(const float* __restrict__ x,
    unsigned* __restrict__ xbf, const float* __restrict__ u0s,
    const float* __restrict__ u0d, float* __restrict__ es, float* __restrict__ ed,
    int Nn) {
  int n = blockIdx.x * 4 + (threadIdx.x >> 6);
  if (n >= Nn) return;
  int l = threadIdx.x & 63;
  int c0 = 2 * l;
  float2 v = *(const float2*)&x[(size_t)n * 128 + c0];
  xbf[(size_t)n * 64 + l] = bf16rne(v.x) | (bf16rne(v.y) << 16);
  float ps[4], pd[4];
#pragma unroll
  for (int h = 0; h < 4; ++h) {
    ps[h] = v.x * u0s[c0 * 4 + h] + v.y * u0s[(c0 + 1) * 4 + h];
    pd[h] = v.x * u0d[c0 * 4 + h] + v.y * u0d[(c0 + 1) * 4 + h];
  }
#pragma unroll
  for (int h = 0; h < 4; ++h)
#pragma unroll
    for (int o = 32; o; o >>= 1) { ps[h] += __shfl_xor(ps[h], o); pd[h] += __shfl_xor(pd[h], o); }
  if (l == 0) {
#pragma unroll
    for (int h = 0; h < 4; ++h) { es[n * 4 + h] = ps[h]; ed[n * 4 + h] = pd[h]; }
  }
}

// --- MFMA GEMM: H(N x NC, fp8) = A(N x 128, bf16) @ W(128 x NC, bf16) -----------

template <int NC>
__global__ __launch_bounds__(256) void gemm_mfma(const unsigned short* __restrict__ Abf,
    const unsigned short* __restrict__ Wt, unsigned char* __restrict__ Hfp,
    int Nrows) {
  constexpr int NT = NC / 16;
  __shared__ unsigned short lw[NC][136];
  int tid = threadIdx.x;
  for (int idx = tid; idx < NC * 16; idx += 256) {
    int c = idx >> 4, k0 = (idx & 15) * 8;
    *(uint4*)&lw[c][k0] = *(const uint4*)&Wt[c * 128 + k0];
  }
  __syncthreads();
  int w = tid >> 6, l = tid & 63;
  int g = l >> 4, i = l & 15;
  int rbase = blockIdx.x * 64 + w * 16;
  int arow = rbase + i; arow = arow < Nrows ? arow : Nrows - 1;
  bf16x8 a[4];
#pragma unroll
  for (int kk = 0; kk < 4; ++kk)
    a[kk] = *(const bf16x8*)&Abf[(size_t)arow * 128 + kk * 32 + g * 8];
  f32x4 acc[NT];
#pragma unroll
  for (int t = 0; t < NT; ++t) acc[t] = (f32x4){0.f, 0.f, 0.f, 0.f};
#pragma unroll
  for (int kk = 0; kk < 4; ++kk) {
#pragma unroll
    for (int t = 0; t < NT; ++t) {
      bf16x8 b = *(const bf16x8*)&lw[t * 16 + i][kk * 32 + g * 8];
      acc[t] = __builtin_amdgcn_mfma_f32_16x16x32_bf16(a[kk], b, acc[t], 0, 0, 0);
    }
  }
  int crow0 = rbase + g * 4;
#pragma unroll
  for (int t = 0; t < NT; ++t)
#pragma unroll
    for (int r = 0; r < 4; ++r) {
      int row = crow0 + r;
      if (row < Nrows)
        Hfp[(size_t)row * NC + t * 16 + i] = fp8enc(acc[t][r]);
    }
}

// --- GAT aggregation (HH=128, 4 heads): 16 lanes/node, 4 nodes/wave, fp8 h ---
// R12-best form: csr-index prefetch only; lane q owns 8 channels (uint2 gather).

template <bool RES, bool WRITE_F32, int NEXT_NH>
__global__ __launch_bounds__(256) void gat_agg128(const uint2* __restrict__ hfp,
    const float* __restrict__ es, const float* __restrict__ ed,
    const int* __restrict__ offs, const int* __restrict__ csr,
    const float* __restrict__ bias, const float* __restrict__ gamma,
    const float* __restrict__ beta, const float* __restrict__ resid,
    float* __restrict__ out_f32, uint4* __restrict__ out_bf,
    const float* __restrict__ uns, const float* __restrict__ und,
    float* __restrict__ es_next, float* __restrict__ ed_next, int Nn) {
  constexpr int CHK = 8;
  int tid = threadIdx.x;
  int l = tid & 63;
  int q = l & 15;
  int n = blockIdx.x * 16 + (tid >> 6) * 4 + (l >> 4);
  if (n >= Nn) return;
  int hh = q >> 2;
  unsigned c0 = q * 8;
  float edn = ed[n * 4 + hh];
  float e0 = es[n * 4 + hh] + edn;   // self loop; softmax shift-invariant
  e0 = e0 > 0.f ? e0 : 0.2f * e0;
  float w0 = __expf(e0);
  float den = w0;
  float acc[8];
  {
    uint2 u = hfp[(unsigned)n * 16 + q];
    f32x2 p0 = __builtin_amdgcn_cvt_pk_f32_fp8(u.x, false);
    f32x2 p1 = __builtin_amdgcn_cvt_pk_f32_fp8(u.x, true);
    f32x2 p2 = __builtin_amdgcn_cvt_pk_f32_fp8(u.y, false);
    f32x2 p3 = __builtin_amdgcn_cvt_pk_f32_fp8(u.y, true);
    acc[0] = w0 * p0.x; acc[1] = w0 * p0.y;
    acc[2] = w0 * p1.x; acc[3] = w0 * p1.y;
    acc[4] = w0 * p2.x; acc[5] = w0 * p2.y;
    acc[6] = w0 * p3.x; acc[7] = w0 * p3.y;
  }
  int beg = offs[n], end = offs[n + 1];
  int s_cur[CHK];
#pragma unroll
  for (int j = 0; j < CHK; ++j) s_cur[j] = (beg + j < end) ? csr[beg + j] : n;
  for (int base = beg; base < end; base += CHK) {
    int s_nxt[CHK];
#pragma unroll
    for (int j = 0; j < CHK; ++j) {
      int idx = base + CHK + j;
      s_nxt[j] = (idx < end) ? csr[idx] : n;
    }
    int cnt = end - base;   // >=1
    uint2 hv[CHK];
#pragma unroll
    for (int j = 0; j < CHK; ++j) hv[j] = hfp[(unsigned)s_cur[j] * 16 + q];
    float w[CHK];
#pragma unroll
    for (int j = 0; j < CHK; ++j) {
      float e = es[s_cur[j] * 4 + hh] + edn;
      e = e > 0.f ? e : 0.2f * e;
      w[j] = (j < cnt) ? __expf(e) : 0.f;
    }
#pragma unroll
    for (int j = 0; j < CHK; ++j) {
      f32x2 p0 = __builtin_amdgcn_cvt_pk_f32_fp8(hv[j].x, false);
      f32x2 p1 = __builtin_amdgcn_cvt_pk_f32_fp8(hv[j].x, true);
      f32x2 p2 = __builtin_amdgcn_cvt_pk_f32_fp8(hv[j].y, false);
      f32x2 p3 = __builtin_amdgcn_cvt_pk_f32_fp8(hv[j].y, true);
      den += w[j];
      acc[0] += w[j] * p0.x; acc[1] += w[j] * p0.y;
      acc[2] += w[j] * p1.x; acc[3] += w[j] * p1.y;
      acc[4] += w[j] * p2.x; acc[5] += w[j] * p2.y;
      acc[6] += w[j] * p3.x; acc[7] += w[j] * p3.y;
    }
#pragma unroll
    for (int j = 0; j < CHK; ++j) s_cur[j] = s_nxt[j];
  }
  float inv = 1.0f / (den + 1e-16f);
  f32x4 bi0 = *(const f32x4*)&bias[c0],  bi1 = *(const f32x4*)&bias[c0 + 4];
  f32x4 ga0 = *(const f32x4*)&gamma[c0], ga1 = *(const f32x4*)&gamma[c0 + 4];
  f32x4 be0 = *(const f32x4*)&beta[c0],  be1 = *(const f32x4*)&beta[c0 + 4];
  f32x4 r0 = (f32x4){0.f,0.f,0.f,0.f}, r1 = r0;
  if (RES) {
    r0 = *(const f32x4*)&resid[(size_t)n * 128 + c0];
    r1 = *(const f32x4*)&resid[(size_t)n * 128 + c0 + 4];
  }
  float o[8];
#pragma unroll
  for (int k = 0; k < 8; ++k) {
    float bi = k < 4 ? bi0[k] : bi1[k - 4];
    float ga = k < 4 ? ga0[k] : ga1[k - 4];
    float be = k < 4 ? be0[k] : be1[k - 4];
    float rv = k < 4 ? r0[k] : r1[k - 4];
    float v = acc[k] * inv + bi;
    if (RES) v += rv;
    v = ga * v * BN_INV + be;
    o[k] = v > 0.f ? v : __expf(v) - 1.f;
  }
  if (WRITE_F32) {
    f32x4 f0 = {o[0], o[1], o[2], o[3]}, f1 = {o[4], o[5], o[6], o[7]};
    *(f32x4*)&out_f32[(size_t)n * 128 + c0] = f0;
    *(f32x4*)&out_f32[(size_t)n * 128 + c0 + 4] = f1;
  }
  uint4 p;
  p.x = bf16rne(o[0]) | (bf16rne(o[1]) << 16);
  p.y = bf16rne(o[2]) | (bf16rne(o[3]) << 16);
  p.z = bf16rne(o[4]) | (bf16rne(o[5]) << 16);
  p.w = bf16rne(o[6]) | (bf16rne(o[7]) << 16);
  out_bf[(unsigned)n * 16 + q] = p;
  // next-layer attention coefficients: es_next = act . u  (16-lane reduce)
  if (NEXT_NH == 4) {
    const f32x4* uns4 = (const f32x4*)uns;
    const f32x4* und4 = (const f32x4*)und;
    f32x4 ps = (f32x4){0.f,0.f,0.f,0.f}, pd = ps;
#pragma unroll
    for (int k = 0; k < 8; ++k) {
      f32x4 us = uns4[c0 + k], ud = und4[c0 + k];
#pragma unroll
      for (int h = 0; h < 4; ++h) { ps[h] += o[k] * us[h]; pd[h] += o[k] * ud[h]; }
    }
#pragma unroll
    for (int h = 0; h < 4; ++h)
#pragma unroll
      for (int m = 1; m < 16; m <<= 1) {
        ps[h] += __shfl_xor(ps[h], m);
        pd[h] += __shfl_xor(pd[h], m);
      }
    if (q == 0) {
#pragma unroll
      for (int h = 0; h < 4; ++h) {
        es_next[n * 4 + h] = ps[h];
        ed_next[n * 4 + h] = pd[h];
      }
    }
  } else {
    float ps = 0.f, pd = 0.f;
#pragma unroll
    for (int k = 0; k < 8; ++k) { ps += o[k] * uns[c0 + k]; pd += o[k] * und[c0 + k]; }
#pragma unroll
    for (int m = 1; m < 16; m <<= 1) { ps += __shfl_xor(ps, m); pd += __shfl_xor(pd, m); }
    if (q == 0) { es_next[n] = ps; ed_next[n] = pd; }
  }
}

// --- layer-2 aggregation (H=1, O=32): 16 lanes/node (2 ch/lane), fp8 h ---

__global__ __launch_bounds__(256) void gat_agg32(const unsigned short* __restrict__ hfp,
    const float* __restrict__ es, const float* __restrict__ ed,
    const int* __restrict__ offs, const int* __restrict__ csr,
    const float* __restrict__ bias, float* __restrict__ h2, int Nn) {
  constexpr int CHK = 8;
  int tid = threadIdx.x;
  int l = tid & 63;
  int q = l & 15;
  int n = blockIdx.x * 16 + (tid >> 6) * 4 + (l >> 4);
  if (n >= Nn) return;
  float edn = ed[n];
  float e0 = es[n] + edn;
  e0 = e0 > 0.f ? e0 : 0.2f * e0;
  float w0 = __expf(e0);
  float den = w0;
  float accx, accy;
  {
    f32x2 p = __builtin_amdgcn_cvt_pk_f32_fp8((unsigned)hfp[(unsigned)n * 16 + q], false);
    accx = w0 * p.x; accy = w0 * p.y;
  }
  int beg = offs[n], end = offs[n + 1];
  int s_cur[CHK];
#pragma unroll
  for (int j = 0; j < CHK; ++j) s_cur[j] = (beg + j < end) ? csr[beg + j] : n;
  for (int base = beg; base < end; base += CHK) {
    int s_nxt[CHK];
#pragma unroll
    for (int j = 0; j < CHK; ++j) {
      int idx = base + CHK + j;
      s_nxt[j] = (idx < end) ? csr[idx] : n;
    }
    int cnt = end - base;
    unsigned short u[CHK];
#pragma unroll
    for (int j = 0; j < CHK; ++j) u[j] = hfp[(unsigned)s_cur[j] * 16 + q];
    float w[CHK];
#pragma unroll
    for (int j = 0; j < CHK; ++j) {
      float e = es[s_cur[j]] + edn;
      e = e > 0.f ? e : 0.2f * e;
      w[j] = (j < cnt) ? __expf(e) : 0.f;
    }
#pragma unroll
    for (int j = 0; j < CHK; ++j) {
      f32x2 p = __builtin_amdgcn_cvt_pk_f32_fp8((unsigned)u[j], false);
      den += w[j];
      accx += w[j] * p.x;
      accy += w[j] * p.y;
    }
#pragma unroll
    for (int j = 0; j < CHK; ++j) s_cur[j] = s_nxt[j];
  }
  float inv = 1.0f / (den + 1e-16f);
  float2 bi = *(const float2*)&bias[2 * q];
  float2 o;
  o.x = accx * inv + bi.x;
  o.y = accy * inv + bi.y;
  *(float2*)&h2[(size_t)n * 32 + 2 * q] = o;
}

// -------- head: mean-pool + conv1d x2 + MLP + log_softmax, 1024 thr/block -------

__global__ __launch_bounds__(1024) void head_kernel(const float* __restrict__ h2,
    const int* __restrict__ batch,
    const float* __restrict__ c0w, const float* __restrict__ c0b,
    const float* __restrict__ cg0, const float* __restrict__ cb0,
    const float* __restrict__ c1w, const float* __restrict__ c1b,
    const float* __restrict__ l1w, const float* __restrict__ l1b,
    const float* __restrict__ l2w, const float* __restrict__ l2b,
    float* __restrict__ out) {
  int b = blockIdx.x;
  int t = threadIdx.x;
  __shared__ float sums[32][32];
  __shared__ float pooled[32];
  __shared__ float z1[32][32];
  __shared__ float z2[16][32];
  __shared__ float emb[16];
  __shared__ float hfc[8];
  __shared__ float logits[10];

  int lo = 0, hi = NNODES;
  while (lo < hi) { int mid = (lo + hi) >> 1; if (batch[mid] < b) lo = mid + 1; else hi = mid; }
  int start = lo;
  lo = 0; hi = NNODES;
  while (lo < hi) { int mid = (lo + hi) >> 1; if (batch[mid] < b + 1) lo = mid + 1; else hi = mid; }
  int end = lo;

  {
    int ch = t & 31, g = t >> 5;     // g in 0..31
    float s = 0.f;
    int i = start + g;
    for (; i + 96 < end; i += 128) {
      float a0 = h2[(size_t)i * 32 + ch];
      float a1 = h2[(size_t)(i + 32) * 32 + ch];
      float a2 = h2[(size_t)(i + 64) * 32 + ch];
      float a3 = h2[(size_t)(i + 96) * 32 + ch];
      s += (a0 + a1) + (a2 + a3);
    }
    for (; i < end; i += 32) s += h2[(size_t)i * 32 + ch];
    sums[g][ch] = s;
  }
  __syncthreads();
  if (t < 32) {
    float s = 0.f;
#pragma unroll
    for (int g = 0; g < 32; ++g) s += sums[g][t];
    float cn = fmaxf((float)(end - start), 1.0f);
    pooled[t] = s / cn;
  }
  __syncthreads();
  // conv1: 1024 outputs, one per thread
  {
    int oc = t >> 5, tt = t & 31;
    float a = c0b[oc];
#pragma unroll
    for (int k = 0; k < 5; ++k) {
      int p = tt + k - 2;
      if (p >= 0 && p < 32) a += pooled[p] * c0w[oc * 5 + k];
    }
    a = cg0[oc] * a * BN_INV + cb0[oc];
    z1[oc][tt] = a > 0.f ? a : __expf(a) - 1.f;
  }
  __syncthreads();
  // conv2: 512 outputs on t<512
  if (t < 512) {
    int oc = t >> 5, tt = t & 31;
    float a = c1b[oc];
    for (int ic = 0; ic < 32; ++ic) {
      const float* wrow = &c1w[(oc * 32 + ic) * 5];
#pragma unroll
      for (int k = 0; k < 5; ++k) {
        int p = tt + k - 2;
        if (p >= 0 && p < 32) a += z1[ic][p] * wrow[k];
      }
    }
    z2[oc][tt] = a;
  }
  __syncthreads();
  if (t < 16) {
    float s = 0.f;
    for (int i = 0; i < 32; ++i) s += z2[t][i];
    s *= (1.0f / 32.0f);
    emb[t] = s;
    out[640 + b * 16 + t] = s;     // output 1: embed (64 x 16)
  }
  __syncthreads();
  if (t < 8) {
    float a = l1b[t];
    for (int i = 0; i < 16; ++i) a += emb[i] * l1w[i * 8 + t];
    hfc[t] = a > 0.f ? a : __expf(a) - 1.f;
  }
  __syncthreads();
  if (t < 10) {
    float a = l2b[t];
    for (int j = 0; j < 8; ++j) a += hfc[j] * l2w[j * 10 + t];
    logits[t] = a;
  }
  __syncthreads();
  if (t == 0) {
    float m = logits[0];
    for (int k = 1; k < 10; ++k) m = fmaxf(m, logits[k]);
    float s = 0.f;
    for (int k = 0; k < 10; ++k) s += __expf(logits[k] - m);
    float lse = m + logf(s);
    for (int k = 0; k < 10; ++k) out[b * 10 + k] = logits[k] - lse;  // output 0
  }
}

// ---------------- launch ----------------

extern "C" void kernel_launch(void* const* d_in, const int* in_sizes, int n_in,
                              void* d_out, int out_size, void* d_ws, size_t ws_size,
                              hipStream_t stream) {
  const float* x   = (const float*)d_in[0];
  const int* eidx  = (const int*)d_in[1];
  const int* esrc  = eidx;
  const int* edst  = eidx + NEDGES;
  const int* batch = (const int*)d_in[2];
  const float* W0  = (const float*)d_in[3];
  const float* a0s = (const float*)d_in[4];
  const float* a0d = (const float*)d_in[5];
  const float* b0  = (const float*)d_in[6];
  const float* W1  = (const float*)d_in[7];
  const float* a1s = (const float*)d_in[8];
  const float* a1d = (const float*)d_in[9];
  const float* b1  = (const float*)d_in[10];
  const float* W2  = (const float*)d_in[11];
  const float* a2s = (const float*)d_in[12];
  const float* a2d = (const float*)d_in[13];
  const float* b2  = (const float*)d_in[14];
  const float* g0  = (const float*)d_in[15];
  const float* be0 = (const float*)d_in[16];
  const float* g1  = (const float*)d_in[17];
  const float* be1 = (const float*)d_in[18];
  const float* c0w = (const float*)d_in[19];
  const float* c0b = (const float*)d_in[20];
  const float* cg0 = (const float*)d_in[21];
  const float* cb0 = (const float*)d_in[22];
  const float* c1w = (const float*)d_in[23];
  const float* c1b = (const float*)d_in[24];
  const float* l1w = (const float*)d_in[25];
  const float* l1b = (const float*)d_in[26];
  const float* l2w = (const float*)d_in[27];
  const float* l2b = (const float*)d_in[28];

  char* ws = (char*)d_ws;
  int*            deg    = (int*)(ws + 0);
  int*            cursor = (int*)(ws + 208448);
  int*            offs   = (int*)(ws + 408448);
  float*          esA    = (float*)(ws + 608512);
  float*          edA    = (float*)(ws + 1408512);
  float*          esB    = (float*)(ws + 2208512);
  float*          edB    = (float*)(ws + 3008512);
  int*            csr    = (int*)(ws + 3808512);
  unsigned*       Abf    = (unsigned*)(ws + 7008512);    // N x 64 uints (bf16 pairs)
  unsigned char*  hfp    = (unsigned char*)(ws + 19808512);  // N x 128 fp8 (l2: N x 32)
  float*          act0   = (float*)(ws + 32608512);      // N x 128 f32 (h2 reuse)
  unsigned short* W0t    = (unsigned short*)(ws + 58208512);
  unsigned short* W1t    = (unsigned short*)(ws + 58241280);
  unsigned short* W2t    = (unsigned short*)(ws + 58274048);
  float*          u0s    = (float*)(ws + 58282240);
  float*          u0d    = (float*)(ws + 58284288);
  float*          u1s    = (float*)(ws + 58286336);
  float*          u1d    = (float*)(ws + 58288384);
  float*          u2s    = (float*)(ws + 58290432);
  float*          u2d    = (float*)(ws + 58290944);
  int*            sloc   = (int*)(ws + 58291456);        // 50000 i32 scan scratch
  int*            sbsum  = (int*)(ws + 58491456);        // 49 i32 block sums
  float*          h2     = act0;
  float*          out    = (float*)d_out;

  hipMemsetAsync(d_ws, 0, 200000, stream);   // deg = 0

  count_deg<<<(NEDGES / 4 + 255) / 256, 256, 0, stream>>>(edst, deg, NEDGES / 4);
  scan_local<<<SCAN_NB, 1024, 0, stream>>>(deg, sloc, sbsum, NNODES);
  scan_finish<<<SCAN_NB, 1024, 0, stream>>>(sloc, sbsum, offs, cursor, NNODES, SCAN_NB);
  fill_csr<<<(NEDGES / 2 + 255) / 256, 256, 0, stream>>>(esrc, edst, cursor, csr, NEDGES / 2);

  prep_kernel<<<147, 256, 0, stream>>>(W0, W1, W2, a0s, a0d, a1s, a1d, a2s, a2d,
                                       W0t, W1t, W2t, u0s, u0d, u1s, u1d, u2s, u2d);
  xprep_kernel<<<NNODES / 4, 256, 0, stream>>>(x, Abf, u0s, u0d, esA, edA, NNODES);

  const int ggrid = (NNODES + 63) / 64;
  const int agrid = (NNODES + 15) / 16;

  // --- layer 0 ---
  gemm_mfma<128><<<ggrid, 256, 0, stream>>>((const unsigned short*)Abf, W0t,
                                            hfp, NNODES);
  gat_agg128<false, true, 4><<<agrid, 256, 0, stream>>>(
      (const uint2*)hfp, esA, edA, offs, csr, b0, g0, be0, nullptr,
      act0, (uint4*)Abf, u1s, u1d, esB, edB, NNODES);

  // --- layer 1 (residual) ---
  gemm_mfma<128><<<ggrid, 256, 0, stream>>>((const unsigned short*)Abf, W1t,
                                            hfp, NNODES);
  gat_agg128<true, false, 1><<<agrid, 256, 0, stream>>>(
      (const uint2*)hfp, esB, edB, offs, csr, b1, g1, be1, act0,
      nullptr, (uint4*)Abf, u2s, u2d, esA, edA, NNODES);

  // --- layer 2 (H=1, O=32) ---
  gemm_mfma<32><<<ggrid, 256, 0, stream>>>((const unsigned short*)Abf, W2t,
                                           hfp, NNODES);
  gat_agg32<<<agrid, 256, 0, stream>>>((const unsigned short*)hfp,
                                       esA, edA, offs, csr, b2, h2, NNODES);

  // --- head (pool fused, 1024 threads) ---
  head_kernel<<<64, 1024, 0, stream>>>(h2, batch, c0w, c0b, cg0, cb0,
                                       c1w, c1b, l1w, l1b, l2w, l2b, out);
}

// Round 18
// 270.173 us; speedup vs baseline: 1.0803x; 1.0803x over previous
//
#include <hip/hip_runtime.h>
#include <hip/hip_bf16.h>

// GATModel: 3-layer GAT (heads 4/4/1) + BN/ELU + residual + mean-pool + conv1d head.
// N=50000 nodes, E=800000 edges (+N self-loops handled analytically).
//
// R17 changes vs R16 (NT-store REVERTED: WRITE_SIZE went UP 52.7->60MB — NT
// bypassed L2 write-combining; fill_csr 56->66us):
//  - fill_csr -> dst-partitioned: 8 partitions keyed on blockIdx&7 (round-robin
//    blockIdx->XCD heuristic; perf-only assumption). Partition p grid-strides
//    the full edge list, processes only dst in [p*6250,(p+1)*6250) -> each
//    csr/cursor line written by ~one XCD -> write-combining works (16x -> ~2x
//    amplification). Reads become 8x sequential re-read (~50MB, L3-fast).
//  - everything else = R15-best (273.8us state).
//
// Workspace (~58.5 MB): see offsets in kernel_launch.

#define NNODES 50000
#define NEDGES 800000
#define BN_INV 0.9999950000374997f  // 1/sqrt(1+1e-5)
#define SCAN_NB 49                  // ceil(NNODES/1024)

typedef __attribute__((ext_vector_type(8))) short bf16x8;
typedef __attribute__((ext_vector_type(4))) float f32x4;
typedef __attribute__((ext_vector_type(2))) float f32x2;

__device__ __forceinline__ unsigned bf16rne(float f) {   // fp32 -> bf16 bits (RNE)
  unsigned u = __float_as_uint(f);
  return (u + 0x7fffu + ((u >> 16) & 1u)) >> 16;
}

__device__ __forceinline__ unsigned char fp8enc(float f) {  // fp32 -> OCP e4m3 (HW RNE/sat)
  return (unsigned char)(__builtin_amdgcn_cvt_pk_fp8_f32(f, f, 0u, false) & 0xffu);
}

// ---------------- CSR build ----------------

__global__ __launch_bounds__(256) void count_deg(const int* __restrict__ dst,
                                                 int* __restrict__ deg, int E4) {
  int i = blockIdx.x * 256 + threadIdx.x;
  if (i < E4) {
    int4 d = *(const int4*)&dst[i * 4];
    atomicAdd(&deg[d.x], 1);
    atomicAdd(&deg[d.y], 1);
    atomicAdd(&deg[d.z], 1);
    atomicAdd(&deg[d.w], 1);
  }
}

// block-local exclusive scan: loc[i] = prefix within block, bsum[b] = block total
__global__ __launch_bounds__(1024) void scan_local(const int* __restrict__ deg,
    int* __restrict__ loc, int* __restrict__ bsum, int Nn) {
  __shared__ int wsum[16];
  __shared__ int woff[17];
  int b = blockIdx.x, t = threadIdx.x, lane = t & 63, w = t >> 6;
  int i = b * 1024 + t;
  int v = (i < Nn) ? deg[i] : 0;
  int incl = v;
#pragma unroll
  for (int o = 1; o < 64; o <<= 1) { int x = __shfl_up(incl, o); if (lane >= o) incl += x; }
  if (lane == 63) wsum[w] = incl;
  __syncthreads();
  if (t == 0) {
    int r = 0;
#pragma unroll
    for (int j = 0; j < 16; ++j) { woff[j] = r; r += wsum[j]; }
    bsum[b] = r;
  }
  __syncthreads();
  if (i < Nn) loc[i] = woff[w] + incl - v;
}

// add scanned block bases; emit offs + cursor; offs[Nn] = total
__global__ __launch_bounds__(1024) void scan_finish(const int* __restrict__ loc,
    const int* __restrict__ bsum, int* __restrict__ offs, int* __restrict__ cursor,
    int Nn, int nb) {
  __shared__ int boff[65];
  int b = blockIdx.x, t = threadIdx.x;
  if (t < 64) {
    int v = (t < nb) ? bsum[t] : 0;
    int incl = v;
#pragma unroll
    for (int o = 1; o < 64; o <<= 1) { int x = __shfl_up(incl, o); if (t >= o) incl += x; }
    boff[t + 1] = incl;
    if (t == 0) boff[0] = 0;
  }
  __syncthreads();
  int base = boff[b];
  int i = b * 1024 + t;
  if (i < Nn) { int o = loc[i] + base; offs[i] = o; cursor[i] = o; }
  if (b == 0 && t == 0) offs[Nn] = boff[nb];
}

// dst-partitioned fill: partition p = blockIdx&7 handles dst in [p*6250,(p+1)*6250).
// Each csr/cursor line is written by ~one XCD -> write-combining effective.
__global__ __launch_bounds__(256) void fill_csr(const int* __restrict__ src,
    const int* __restrict__ dst, int* __restrict__ cursor,
    int* __restrict__ csr, int E4) {
  int part = blockIdx.x & 7;
  int lo = part * (NNODES / 8), hi = lo + (NNODES / 8);
  int nblk = gridDim.x >> 3;
  int blk = blockIdx.x >> 3;
  for (int i = blk * 256 + threadIdx.x; i < E4; i += nblk * 256) {
    int4 d = *(const int4*)&dst[i * 4];
    int4 s = *(const int4*)&src[i * 4];
    if (d.x >= lo && d.x < hi) csr[atomicAdd(&cursor[d.x], 1)] = s.x;
    if (d.y >= lo && d.y < hi) csr[atomicAdd(&cursor[d.y], 1)] = s.y;
    if (d.z >= lo && d.z < hi) csr[atomicAdd(&cursor[d.z], 1)] = s.z;
    if (d.w >= lo && d.w < hi) csr[atomicAdd(&cursor[d.w], 1)] = s.w;
  }
}

// --------- prep: W0t/W1t/W2t (bf16, transposed) + u = W @ a_{s,d} vectors --------

__global__ __launch_bounds__(256) void prep_kernel(
    const float* __restrict__ W0, const float* __restrict__ W1, const float* __restrict__ W2,
    const float* __restrict__ a0s, const float* __restrict__ a0d,
    const float* __restrict__ a1s, const float* __restrict__ a1d,
    const float* __restrict__ a2s, const float* __restrict__ a2d,
    unsigned short* __restrict__ W0t, unsigned short* __restrict__ W1t,
    unsigned short* __restrict__ W2t,
    float* __restrict__ u0s, float* __restrict__ u0d,
    float* __restrict__ u1s, float* __restrict__ u1d,
    float* __restrict__ u2s, float* __restrict__ u2d) {
  int b = blockIdx.x, t = threadIdx.x;
  if (b < 64) {                       // W0t
    int idx = b * 256 + t; int c = idx >> 7, k = idx & 127;
    W0t[idx] = (unsigned short)bf16rne(W0[k * 128 + c]);
  } else if (b < 128) {               // W1t
    int idx = (b - 64) * 256 + t; int c = idx >> 7, k = idx & 127;
    W1t[idx] = (unsigned short)bf16rne(W1[k * 128 + c]);
  } else if (b < 144) {               // W2t (32 x 128)
    int idx = (b - 128) * 256 + t; int c = idx >> 7, k = idx & 127;
    W2t[idx] = (unsigned short)bf16rne(W2[k * 32 + c]);
  } else if (b == 144) {              // u0
    for (int it = 0; it < 4; ++it) {
      int idx = it * 256 + t;         // 0..1023
      int k = idx >> 3, rem = idx & 7, h = rem >> 1, sd = rem & 1;
      const float* av = sd ? a0d : a0s;
      float s = 0.f;
      for (int o = 0; o < 32; ++o) s += W0[k * 128 + h * 32 + o] * av[h * 32 + o];
      (sd ? u0d : u0s)[k * 4 + h] = s;
    }
  } else if (b == 145) {              // u1
    for (int it = 0; it < 4; ++it) {
      int idx = it * 256 + t;
      int k = idx >> 3, rem = idx & 7, h = rem >> 1, sd = rem & 1;
      const float* av = sd ? a1d : a1s;
      float s = 0.f;
      for (int o = 0; o < 32; ++o) s += W1[k * 128 + h * 32 + o] * av[h * 32 + o];
      (sd ? u1d : u1s)[k * 4 + h] = s;
    }
  } else {                            // u2 (256 outputs)
    int k = t >> 1, sd = t & 1;
    const float* av = sd ? a2d : a2s;
    float s = 0.f;
    for (int o = 0; o < 32; ++o) s += W2[k * 32 + o] * av[o];
    (sd ? u2d : u2s)[k] = s;
  }
}

// --------- xprep: x(f32) -> xbf(bf16) + es0/ed0 = x . u0 (one wave per node) -----

__global__ __launch_bounds__(256) void xprep_kernel(const float* __restrict__ x,
    unsigned* __restrict__ xbf, const float* __restrict__ u0s,
    const float* __restrict__ u0d, float* __restrict__ es, float* __restrict__ ed,
    int Nn) {
  int n = blockIdx.x * 4 + (threadIdx.x >> 6);
  if (n >= Nn) return;
  int l = threadIdx.x & 63;
  int c0 = 2 * l;
  float2 v = *(const float2*)&x[(size_t)n * 128 + c0];
  xbf[(size_t)n * 64 + l] = bf16rne(v.x) | (bf16rne(v.y) << 16);
  float ps[4], pd[4];
#pragma unroll
  for (int h = 0; h < 4; ++h) {
    ps[h] = v.x * u0s[c0 * 4 + h] + v.y * u0s[(c0 + 1) * 4 + h];
    pd[h] = v.x * u0d[c0 * 4 + h] + v.y * u0d[(c0 + 1) * 4 + h];
  }
#pragma unroll
  for (int h = 0; h < 4; ++h)
#pragma unroll
    for (int o = 32; o; o >>= 1) { ps[h] += __shfl_xor(ps[h], o); pd[h] += __shfl_xor(pd[h], o); }
  if (l == 0) {
#pragma unroll
    for (int h = 0; h < 4; ++h) { es[n * 4 + h] = ps[h]; ed[n * 4 + h] = pd[h]; }
  }
}

// --- MFMA GEMM: H(N x NC, fp8) = A(N x 128, bf16) @ W(128 x NC, bf16) -----------

template <int NC>
__global__ __launch_bounds__(256) void gemm_mfma(const unsigned short* __restrict__ Abf,
    const unsigned short* __restrict__ Wt, unsigned char* __restrict__ Hfp,
    int Nrows) {
  constexpr int NT = NC / 16;
  __shared__ unsigned short lw[NC][136];
  int tid = threadIdx.x;
  for (int idx = tid; idx < NC * 16; idx += 256) {
    int c = idx >> 4, k0 = (idx & 15) * 8;
    *(uint4*)&lw[c][k0] = *(const uint4*)&Wt[c * 128 + k0];
  }
  __syncthreads();
  int w = tid >> 6, l = tid & 63;
  int g = l >> 4, i = l & 15;
  int rbase = blockIdx.x * 64 + w * 16;
  int arow = rbase + i; arow = arow < Nrows ? arow : Nrows - 1;
  bf16x8 a[4];
#pragma unroll
  for (int kk = 0; kk < 4; ++kk)
    a[kk] = *(const bf16x8*)&Abf[(size_t)arow * 128 + kk * 32 + g * 8];
  f32x4 acc[NT];
#pragma unroll
  for (int t = 0; t < NT; ++t) acc[t] = (f32x4){0.f, 0.f, 0.f, 0.f};
#pragma unroll
  for (int kk = 0; kk < 4; ++kk) {
#pragma unroll
    for (int t = 0; t < NT; ++t) {
      bf16x8 b = *(const bf16x8*)&lw[t * 16 + i][kk * 32 + g * 8];
      acc[t] = __builtin_amdgcn_mfma_f32_16x16x32_bf16(a[kk], b, acc[t], 0, 0, 0);
    }
  }
  int crow0 = rbase + g * 4;
#pragma unroll
  for (int t = 0; t < NT; ++t)
#pragma unroll
    for (int r = 0; r < 4; ++r) {
      int row = crow0 + r;
      if (row < Nrows)
        Hfp[(size_t)row * NC + t * 16 + i] = fp8enc(acc[t][r]);
    }
}

// --- GAT aggregation (HH=128, 4 heads): 16 lanes/node, 4 nodes/wave, fp8 h ---
// R12-best form: csr-index prefetch only; lane q owns 8 channels (uint2 gather).

template <bool RES, bool WRITE_F32, int NEXT_NH>
__global__ __launch_bounds__(256) void gat_agg128(const uint2* __restrict__ hfp,
    const float* __restrict__ es, const float* __restrict__ ed,
    const int* __restrict__ offs, const int* __restrict__ csr,
    const float* __restrict__ bias, const float* __restrict__ gamma,
    const float* __restrict__ beta, const float* __restrict__ resid,
    float* __restrict__ out_f32, uint4* __restrict__ out_bf,
    const float* __restrict__ uns, const float* __restrict__ und,
    float* __restrict__ es_next, float* __restrict__ ed_next, int Nn) {
  constexpr int CHK = 8;
  int tid = threadIdx.x;
  int l = tid & 63;
  int q = l & 15;
  int n = blockIdx.x * 16 + (tid >> 6) * 4 + (l >> 4);
  if (n >= Nn) return;
  int hh = q >> 2;
  unsigned c0 = q * 8;
  float edn = ed[n * 4 + hh];
  float e0 = es[n * 4 + hh] + edn;   // self loop; softmax shift-invariant
  e0 = e0 > 0.f ? e0 : 0.2f * e0;
  float w0 = __expf(e0);
  float den = w0;
  float acc[8];
  {
    uint2 u = hfp[(unsigned)n * 16 + q];
    f32x2 p0 = __builtin_amdgcn_cvt_pk_f32_fp8(u.x, false);
    f32x2 p1 = __builtin_amdgcn_cvt_pk_f32_fp8(u.x, true);
    f32x2 p2 = __builtin_amdgcn_cvt_pk_f32_fp8(u.y, false);
    f32x2 p3 = __builtin_amdgcn_cvt_pk_f32_fp8(u.y, true);
    acc[0] = w0 * p0.x; acc[1] = w0 * p0.y;
    acc[2] = w0 * p1.x; acc[3] = w0 * p1.y;
    acc[4] = w0 * p2.x; acc[5] = w0 * p2.y;
    acc[6] = w0 * p3.x; acc[7] = w0 * p3.y;
  }
  int beg = offs[n], end = offs[n + 1];
  int s_cur[CHK];
#pragma unroll
  for (int j = 0; j < CHK; ++j) s_cur[j] = (beg + j < end) ? csr[beg + j] : n;
  for (int base = beg; base < end; base += CHK) {
    int s_nxt[CHK];
#pragma unroll
    for (int j = 0; j < CHK; ++j) {
      int idx = base + CHK + j;
      s_nxt[j] = (idx < end) ? csr[idx] : n;
    }
    int cnt = end - base;   // >=1
    uint2 hv[CHK];
#pragma unroll
    for (int j = 0; j < CHK; ++j) hv[j] = hfp[(unsigned)s_cur[j] * 16 + q];
    float w[CHK];
#pragma unroll
    for (int j = 0; j < CHK; ++j) {
      float e = es[s_cur[j] * 4 + hh] + edn;
      e = e > 0.f ? e : 0.2f * e;
      w[j] = (j < cnt) ? __expf(e) : 0.f;
    }
#pragma unroll
    for (int j = 0; j < CHK; ++j) {
      f32x2 p0 = __builtin_amdgcn_cvt_pk_f32_fp8(hv[j].x, false);
      f32x2 p1 = __builtin_amdgcn_cvt_pk_f32_fp8(hv[j].x, true);
      f32x2 p2 = __builtin_amdgcn_cvt_pk_f32_fp8(hv[j].y, false);
      f32x2 p3 = __builtin_amdgcn_cvt_pk_f32_fp8(hv[j].y, true);
      den += w[j];
      acc[0] += w[j] * p0.x; acc[1] += w[j] * p0.y;
      acc[2] += w[j] * p1.x; acc[3] += w[j] * p1.y;
      acc[4] += w[j] * p2.x; acc[5] += w[j] * p2.y;
      acc[6] += w[j] * p3.x; acc[7] += w[j] * p3.y;
    }
#pragma unroll
    for (int j = 0; j < CHK; ++j) s_cur[j] = s_nxt[j];
  }
  float inv = 1.0f / (den + 1e-16f);
  f32x4 bi0 = *(const f32x4*)&bias[c0],  bi1 = *(const f32x4*)&bias[c0 + 4];
  f32x4 ga0 = *(const f32x4*)&gamma[c0], ga1 = *(const f32x4*)&gamma[c0 + 4];
  f32x4 be0 = *(const f32x4*)&beta[c0],  be1 = *(const f32x4*)&beta[c0 + 4];
  f32x4 r0 = (f32x4){0.f,0.f,0.f,0.f}, r1 = r0;
  if (RES) {
    r0 = *(const f32x4*)&resid[(size_t)n * 128 + c0];
    r1 = *(const f32x4*)&resid[(size_t)n * 128 + c0 + 4];
  }
  float o[8];
#pragma unroll
  for (int k = 0; k < 8; ++k) {
    float bi = k < 4 ? bi0[k] : bi1[k - 4];
    float ga = k < 4 ? ga0[k] : ga1[k - 4];
    float be = k < 4 ? be0[k] : be1[k - 4];
    float rv = k < 4 ? r0[k] : r1[k - 4];
    float v = acc[k] * inv + bi;
    if (RES) v += rv;
    v = ga * v * BN_INV + be;
    o[k] = v > 0.f ? v : __expf(v) - 1.f;
  }
  if (WRITE_F32) {
    f32x4 f0 = {o[0], o[1], o[2], o[3]}, f1 = {o[4], o[5], o[6], o[7]};
    *(f32x4*)&out_f32[(size_t)n * 128 + c0] = f0;
    *(f32x4*)&out_f32[(size_t)n * 128 + c0 + 4] = f1;
  }
  uint4 p;
  p.x = bf16rne(o[0]) | (bf16rne(o[1]) << 16);
  p.y = bf16rne(o[2]) | (bf16rne(o[3]) << 16);
  p.z = bf16rne(o[4]) | (bf16rne(o[5]) << 16);
  p.w = bf16rne(o[6]) | (bf16rne(o[7]) << 16);
  out_bf[(unsigned)n * 16 + q] = p;
  // next-layer attention coefficients: es_next = act . u  (16-lane reduce)
  if (NEXT_NH == 4) {
    const f32x4* uns4 = (const f32x4*)uns;
    const f32x4* und4 = (const f32x4*)und;
    f32x4 ps = (f32x4){0.f,0.f,0.f,0.f}, pd = ps;
#pragma unroll
    for (int k = 0; k < 8; ++k) {
      f32x4 us = uns4[c0 + k], ud = und4[c0 + k];
#pragma unroll
      for (int h = 0; h < 4; ++h) { ps[h] += o[k] * us[h]; pd[h] += o[k] * ud[h]; }
    }
#pragma unroll
    for (int h = 0; h < 4; ++h)
#pragma unroll
      for (int m = 1; m < 16; m <<= 1) {
        ps[h] += __shfl_xor(ps[h], m);
        pd[h] += __shfl_xor(pd[h], m);
      }
    if (q == 0) {
#pragma unroll
      for (int h = 0; h < 4; ++h) {
        es_next[n * 4 + h] = ps[h];
        ed_next[n * 4 + h] = pd[h];
      }
    }
  } else {
    float ps = 0.f, pd = 0.f;
#pragma unroll
    for (int k = 0; k < 8; ++k) { ps += o[k] * uns[c0 + k]; pd += o[k] * und[c0 + k]; }
#pragma unroll
    for (int m = 1; m < 16; m <<= 1) { ps += __shfl_xor(ps, m); pd += __shfl_xor(pd, m); }
    if (q == 0) { es_next[n] = ps; ed_next[n] = pd; }
  }
}

// --- layer-2 aggregation (H=1, O=32): 16 lanes/node (2 ch/lane), fp8 h ---

__global__ __launch_bounds__(256) void gat_agg32(const unsigned short* __restrict__ hfp,
    const float* __restrict__ es, const float* __restrict__ ed,
    const int* __restrict__ offs, const int* __restrict__ csr,
    const float* __restrict__ bias, float* __restrict__ h2, int Nn) {
  constexpr int CHK = 8;
  int tid = threadIdx.x;
  int l = tid & 63;
  int q = l & 15;
  int n = blockIdx.x * 16 + (tid >> 6) * 4 + (l >> 4);
  if (n >= Nn) return;
  float edn = ed[n];
  float e0 = es[n] + edn;
  e0 = e0 > 0.f ? e0 : 0.2f * e0;
  float w0 = __expf(e0);
  float den = w0;
  float accx, accy;
  {
    f32x2 p = __builtin_amdgcn_cvt_pk_f32_fp8((unsigned)hfp[(unsigned)n * 16 + q], false);
    accx = w0 * p.x; accy = w0 * p.y;
  }
  int beg = offs[n], end = offs[n + 1];
  int s_cur[CHK];
#pragma unroll
  for (int j = 0; j < CHK; ++j) s_cur[j] = (beg + j < end) ? csr[beg + j] : n;
  for (int base = beg; base < end; base += CHK) {
    int s_nxt[CHK];
#pragma unroll
    for (int j = 0; j < CHK; ++j) {
      int idx = base + CHK + j;
      s_nxt[j] = (idx < end) ? csr[idx] : n;
    }
    int cnt = end - base;
    unsigned short u[CHK];
#pragma unroll
    for (int j = 0; j < CHK; ++j) u[j] = hfp[(unsigned)s_cur[j] * 16 + q];
    float w[CHK];
#pragma unroll
    for (int j = 0; j < CHK; ++j) {
      float e = es[s_cur[j]] + edn;
      e = e > 0.f ? e : 0.2f * e;
      w[j] = (j < cnt) ? __expf(e) : 0.f;
    }
#pragma unroll
    for (int j = 0; j < CHK; ++j) {
      f32x2 p = __builtin_amdgcn_cvt_pk_f32_fp8((unsigned)u[j], false);
      den += w[j];
      accx += w[j] * p.x;
      accy += w[j] * p.y;
    }
#pragma unroll
    for (int j = 0; j < CHK; ++j) s_cur[j] = s_nxt[j];
  }
  float inv = 1.0f / (den + 1e-16f);
  float2 bi = *(const float2*)&bias[2 * q];
  float2 o;
  o.x = accx * inv + bi.x;
  o.y = accy * inv + bi.y;
  *(float2*)&h2[(size_t)n * 32 + 2 * q] = o;
}

// -------- head: mean-pool + conv1d x2 + MLP + log_softmax, 1024 thr/block -------

__global__ __launch_bounds__(1024) void head_kernel(const float* __restrict__ h2,
    const int* __restrict__ batch,
    const float* __restrict__ c0w, const float* __restrict__ c0b,
    const float* __restrict__ cg0, const float* __restrict__ cb0,
    const float* __restrict__ c1w, const float* __restrict__ c1b,
    const float* __restrict__ l1w, const float* __restrict__ l1b,
    const float* __restrict__ l2w, const float* __restrict__ l2b,
    float* __restrict__ out) {
  int b = blockIdx.x;
  int t = threadIdx.x;
  __shared__ float sums[32][32];
  __shared__ float pooled[32];
  __shared__ float z1[32][32];
  __shared__ float z2[16][32];
  __shared__ float emb[16];
  __shared__ float hfc[8];
  __shared__ float logits[10];

  int lo = 0, hi = NNODES;
  while (lo < hi) { int mid = (lo + hi) >> 1; if (batch[mid] < b) lo = mid + 1; else hi = mid; }
  int start = lo;
  lo = 0; hi = NNODES;
  while (lo < hi) { int mid = (lo + hi) >> 1; if (batch[mid] < b + 1) lo = mid + 1; else hi = mid; }
  int end = lo;

  {
    int ch = t & 31, g = t >> 5;     // g in 0..31
    float s = 0.f;
    int i = start + g;
    for (; i + 96 < end; i += 128) {
      float a0 = h2[(size_t)i * 32 + ch];
      float a1 = h2[(size_t)(i + 32) * 32 + ch];
      float a2 = h2[(size_t)(i + 64) * 32 + ch];
      float a3 = h2[(size_t)(i + 96) * 32 + ch];
      s += (a0 + a1) + (a2 + a3);
    }
    for (; i < end; i += 32) s += h2[(size_t)i * 32 + ch];
    sums[g][ch] = s;
  }
  __syncthreads();
  if (t < 32) {
    float s = 0.f;
#pragma unroll
    for (int g = 0; g < 32; ++g) s += sums[g][t];
    float cn = fmaxf((float)(end - start), 1.0f);
    pooled[t] = s / cn;
  }
  __syncthreads();
  // conv1: 1024 outputs, one per thread
  {
    int oc = t >> 5, tt = t & 31;
    float a = c0b[oc];
#pragma unroll
    for (int k = 0; k < 5; ++k) {
      int p = tt + k - 2;
      if (p >= 0 && p < 32) a += pooled[p] * c0w[oc * 5 + k];
    }
    a = cg0[oc] * a * BN_INV + cb0[oc];
    z1[oc][tt] = a > 0.f ? a : __expf(a) - 1.f;
  }
  __syncthreads();
  // conv2: 512 outputs on t<512
  if (t < 512) {
    int oc = t >> 5, tt = t & 31;
    float a = c1b[oc];
    for (int ic = 0; ic < 32; ++ic) {
      const float* wrow = &c1w[(oc * 32 + ic) * 5];
#pragma unroll
      for (int k = 0; k < 5; ++k) {
        int p = tt + k - 2;
        if (p >= 0 && p < 32) a += z1[ic][p] * wrow[k];
      }
    }
    z2[oc][tt] = a;
  }
  __syncthreads();
  if (t < 16) {
    float s = 0.f;
    for (int i = 0; i < 32; ++i) s += z2[t][i];
    s *= (1.0f / 32.0f);
    emb[t] = s;
    out[640 + b * 16 + t] = s;     // output 1: embed (64 x 16)
  }
  __syncthreads();
  if (t < 8) {
    float a = l1b[t];
    for (int i = 0; i < 16; ++i) a += emb[i] * l1w[i * 8 + t];
    hfc[t] = a > 0.f ? a : __expf(a) - 1.f;
  }
  __syncthreads();
  if (t < 10) {
    float a = l2b[t];
    for (int j = 0; j < 8; ++j) a += hfc[j] * l2w[j * 10 + t];
    logits[t] = a;
  }
  __syncthreads();
  if (t == 0) {
    float m = logits[0];
    for (int k = 1; k < 10; ++k) m = fmaxf(m, logits[k]);
    float s = 0.f;
    for (int k = 0; k < 10; ++k) s += __expf(logits[k] - m);
    float lse = m + logf(s);
    for (int k = 0; k < 10; ++k) out[b * 10 + k] = logits[k] - lse;  // output 0
  }
}

// ---------------- launch ----------------

extern "C" void kernel_launch(void* const* d_in, const int* in_sizes, int n_in,
                              void* d_out, int out_size, void* d_ws, size_t ws_size,
                              hipStream_t stream) {
  const float* x   = (const float*)d_in[0];
  const int* eidx  = (const int*)d_in[1];
  const int* esrc  = eidx;
  const int* edst  = eidx + NEDGES;
  const int* batch = (const int*)d_in[2];
  const float* W0  = (const float*)d_in[3];
  const float* a0s = (const float*)d_in[4];
  const float* a0d = (const float*)d_in[5];
  const float* b0  = (const float*)d_in[6];
  const float* W1  = (const float*)d_in[7];
  const float* a1s = (const float*)d_in[8];
  const float* a1d = (const float*)d_in[9];
  const float* b1  = (const float*)d_in[10];
  const float* W2  = (const float*)d_in[11];
  const float* a2s = (const float*)d_in[12];
  const float* a2d = (const float*)d_in[13];
  const float* b2  = (const float*)d_in[14];
  const float* g0  = (const float*)d_in[15];
  const float* be0 = (const float*)d_in[16];
  const float* g1  = (const float*)d_in[17];
  const float* be1 = (const float*)d_in[18];
  const float* c0w = (const float*)d_in[19];
  const float* c0b = (const float*)d_in[20];
  const float* cg0 = (const float*)d_in[21];
  const float* cb0 = (const float*)d_in[22];
  const float* c1w = (const float*)d_in[23];
  const float* c1b = (const float*)d_in[24];
  const float* l1w = (const float*)d_in[25];
  const float* l1b = (const float*)d_in[26];
  const float* l2w = (const float*)d_in[27];
  const float* l2b = (const float*)d_in[28];

  char* ws = (char*)d_ws;
  int*            deg    = (int*)(ws + 0);
  int*            cursor = (int*)(ws + 208448);
  int*            offs   = (int*)(ws + 408448);
  float*          esA    = (float*)(ws + 608512);
  float*          edA    = (float*)(ws + 1408512);
  float*          esB    = (float*)(ws + 2208512);
  float*          edB    = (float*)(ws + 3008512);
  int*            csr    = (int*)(ws + 3808512);
  unsigned*       Abf    = (unsigned*)(ws + 7008512);    // N x 64 uints (bf16 pairs)
  unsigned char*  hfp    = (unsigned char*)(ws + 19808512);  // N x 128 fp8 (l2: N x 32)
  float*          act0   = (float*)(ws + 32608512);      // N x 128 f32 (h2 reuse)
  unsigned short* W0t    = (unsigned short*)(ws + 58208512);
  unsigned short* W1t    = (unsigned short*)(ws + 58241280);
  unsigned short* W2t    = (unsigned short*)(ws + 58274048);
  float*          u0s    = (float*)(ws + 58282240);
  float*          u0d    = (float*)(ws + 58284288);
  float*          u1s    = (float*)(ws + 58286336);
  float*          u1d    = (float*)(ws + 58288384);
  float*          u2s    = (float*)(ws + 58290432);
  float*          u2d    = (float*)(ws + 58290944);
  int*            sloc   = (int*)(ws + 58291456);        // 50000 i32 scan scratch
  int*            sbsum  = (int*)(ws + 58491456);        // 49 i32 block sums
  float*          h2     = act0;
  float*          out    = (float*)d_out;

  hipMemsetAsync(d_ws, 0, 200000, stream);   // deg = 0

  count_deg<<<(NEDGES / 4 + 255) / 256, 256, 0, stream>>>(edst, deg, NEDGES / 4);
  scan_local<<<SCAN_NB, 1024, 0, stream>>>(deg, sloc, sbsum, NNODES);
  scan_finish<<<SCAN_NB, 1024, 0, stream>>>(sloc, sbsum, offs, cursor, NNODES, SCAN_NB);
  fill_csr<<<1024, 256, 0, stream>>>(esrc, edst, cursor, csr, NEDGES / 4);

  prep_kernel<<<147, 256, 0, stream>>>(W0, W1, W2, a0s, a0d, a1s, a1d, a2s, a2d,
                                       W0t, W1t, W2t, u0s, u0d, u1s, u1d, u2s, u2d);
  xprep_kernel<<<NNODES / 4, 256, 0, stream>>>(x, Abf, u0s, u0d, esA, edA, NNODES);

  const int ggrid = (NNODES + 63) / 64;
  const int agrid = (NNODES + 15) / 16;

  // --- layer 0 ---
  gemm_mfma<128><<<ggrid, 256, 0, stream>>>((const unsigned short*)Abf, W0t,
                                            hfp, NNODES);
  gat_agg128<false, true, 4><<<agrid, 256, 0, stream>>>(
      (const uint2*)hfp, esA, edA, offs, csr, b0, g0, be0, nullptr,
      act0, (uint4*)Abf, u1s, u1d, esB, edB, NNODES);

  // --- layer 1 (residual) ---
  gemm_mfma<128><<<ggrid, 256, 0, stream>>>((const unsigned short*)Abf, W1t,
                                            hfp, NNODES);
  gat_agg128<true, false, 1><<<agrid, 256, 0, stream>>>(
      (const uint2*)hfp, esB, edB, offs, csr, b1, g1, be1, act0,
      nullptr, (uint4*)Abf, u2s, u2d, esA, edA, NNODES);

  // --- layer 2 (H=1, O=32) ---
  gemm_mfma<32><<<ggrid, 256, 0, stream>>>((const unsigned short*)Abf, W2t,
                                           hfp, NNODES);
  gat_agg32<<<agrid, 256, 0, stream>>>((const unsigned short*)hfp,
                                       esA, edA, offs, csr, b2, h2, NNODES);

  // --- head (pool fused, 1024 threads) ---
  head_kernel<<<64, 1024, 0, stream>>>(h2, batch, c0w, c0b, cg0, cb0,
                                       c1w, c1b, l1w, l1b, l2w, l2b, out);
}

// Round 19
// 266.957 us; speedup vs baseline: 1.0933x; 1.0120x over previous
//
#include <hip/hip_runtime.h>
#include <hip/hip_bf16.h>

// GATModel: 3-layer GAT (heads 4/4/1) + BN/ELU + residual + mean-pool + conv1d head.
// N=50000 nodes, E=800000 edges (+N self-loops handled analytically).
//
// R18 changes vs R17-best (270.2us; top-5 = pure gat_agg128 ~55.7us x2, shown
// to be L2-miss-queue bound — structural floor):
//  - bf16 residual: layer-1 agg reads resid from Abf (bf16, already written by
//    layer-0 epilogue) instead of f32 act0 -> layer-0 agg's 25.6MB f32 write
//    and layer-1's 25.6MB f32 read eliminated. Per-thread slot ownership makes
//    the Abf read-then-overwrite race-free.
//  - count_deg dst-partitioned (same proven R17 fill_csr pattern): deg lines
//    become single-XCD under atomics; dst re-read 8x sequential (L3-fast).
//
// Workspace (~58.5 MB): see offsets in kernel_launch.

#define NNODES 50000
#define NEDGES 800000
#define BN_INV 0.9999950000374997f  // 1/sqrt(1+1e-5)
#define SCAN_NB 49                  // ceil(NNODES/1024)

typedef __attribute__((ext_vector_type(8))) short bf16x8;
typedef __attribute__((ext_vector_type(4))) float f32x4;
typedef __attribute__((ext_vector_type(2))) float f32x2;

__device__ __forceinline__ unsigned bf16rne(float f) {   // fp32 -> bf16 bits (RNE)
  unsigned u = __float_as_uint(f);
  return (u + 0x7fffu + ((u >> 16) & 1u)) >> 16;
}
__device__ __forceinline__ float bf_lo(unsigned u) { return __uint_as_float(u << 16); }
__device__ __forceinline__ float bf_hi(unsigned u) { return __uint_as_float(u & 0xffff0000u); }

__device__ __forceinline__ unsigned char fp8enc(float f) {  // fp32 -> OCP e4m3 (HW RNE/sat)
  return (unsigned char)(__builtin_amdgcn_cvt_pk_fp8_f32(f, f, 0u, false) & 0xffu);
}

// ---------------- CSR build ----------------

// dst-partitioned histogram: partition p = blockIdx&7 counts dst in its range.
__global__ __launch_bounds__(256) void count_deg(const int* __restrict__ dst,
                                                 int* __restrict__ deg, int E4) {
  int part = blockIdx.x & 7;
  int lo = part * (NNODES / 8), hi = lo + (NNODES / 8);
  int nblk = gridDim.x >> 3;
  int blk = blockIdx.x >> 3;
  for (int i = blk * 256 + threadIdx.x; i < E4; i += nblk * 256) {
    int4 d = *(const int4*)&dst[i * 4];
    if (d.x >= lo && d.x < hi) atomicAdd(&deg[d.x], 1);
    if (d.y >= lo && d.y < hi) atomicAdd(&deg[d.y], 1);
    if (d.z >= lo && d.z < hi) atomicAdd(&deg[d.z], 1);
    if (d.w >= lo && d.w < hi) atomicAdd(&deg[d.w], 1);
  }
}

// block-local exclusive scan: loc[i] = prefix within block, bsum[b] = block total
__global__ __launch_bounds__(1024) void scan_local(const int* __restrict__ deg,
    int* __restrict__ loc, int* __restrict__ bsum, int Nn) {
  __shared__ int wsum[16];
  __shared__ int woff[17];
  int b = blockIdx.x, t = threadIdx.x, lane = t & 63, w = t >> 6;
  int i = b * 1024 + t;
  int v = (i < Nn) ? deg[i] : 0;
  int incl = v;
#pragma unroll
  for (int o = 1; o < 64; o <<= 1) { int x = __shfl_up(incl, o); if (lane >= o) incl += x; }
  if (lane == 63) wsum[w] = incl;
  __syncthreads();
  if (t == 0) {
    int r = 0;
#pragma unroll
    for (int j = 0; j < 16; ++j) { woff[j] = r; r += wsum[j]; }
    bsum[b] = r;
  }
  __syncthreads();
  if (i < Nn) loc[i] = woff[w] + incl - v;
}

// add scanned block bases; emit offs + cursor; offs[Nn] = total
__global__ __launch_bounds__(1024) void scan_finish(const int* __restrict__ loc,
    const int* __restrict__ bsum, int* __restrict__ offs, int* __restrict__ cursor,
    int Nn, int nb) {
  __shared__ int boff[65];
  int b = blockIdx.x, t = threadIdx.x;
  if (t < 64) {
    int v = (t < nb) ? bsum[t] : 0;
    int incl = v;
#pragma unroll
    for (int o = 1; o < 64; o <<= 1) { int x = __shfl_up(incl, o); if (t >= o) incl += x; }
    boff[t + 1] = incl;
    if (t == 0) boff[0] = 0;
  }
  __syncthreads();
  int base = boff[b];
  int i = b * 1024 + t;
  if (i < Nn) { int o = loc[i] + base; offs[i] = o; cursor[i] = o; }
  if (b == 0 && t == 0) offs[Nn] = boff[nb];
}

// dst-partitioned fill (R17-proven): each csr/cursor line written by ~one XCD.
__global__ __launch_bounds__(256) void fill_csr(const int* __restrict__ src,
    const int* __restrict__ dst, int* __restrict__ cursor,
    int* __restrict__ csr, int E4) {
  int part = blockIdx.x & 7;
  int lo = part * (NNODES / 8), hi = lo + (NNODES / 8);
  int nblk = gridDim.x >> 3;
  int blk = blockIdx.x >> 3;
  for (int i = blk * 256 + threadIdx.x; i < E4; i += nblk * 256) {
    int4 d = *(const int4*)&dst[i * 4];
    int4 s = *(const int4*)&src[i * 4];
    if (d.x >= lo && d.x < hi) csr[atomicAdd(&cursor[d.x], 1)] = s.x;
    if (d.y >= lo && d.y < hi) csr[atomicAdd(&cursor[d.y], 1)] = s.y;
    if (d.z >= lo && d.z < hi) csr[atomicAdd(&cursor[d.z], 1)] = s.z;
    if (d.w >= lo && d.w < hi) csr[atomicAdd(&cursor[d.w], 1)] = s.w;
  }
}

// --------- prep: W0t/W1t/W2t (bf16, transposed) + u = W @ a_{s,d} vectors --------

__global__ __launch_bounds__(256) void prep_kernel(
    const float* __restrict__ W0, const float* __restrict__ W1, const float* __restrict__ W2,
    const float* __restrict__ a0s, const float* __restrict__ a0d,
    const float* __restrict__ a1s, const float* __restrict__ a1d,
    const float* __restrict__ a2s, const float* __restrict__ a2d,
    unsigned short* __restrict__ W0t, unsigned short* __restrict__ W1t,
    unsigned short* __restrict__ W2t,
    float* __restrict__ u0s, float* __restrict__ u0d,
    float* __restrict__ u1s, float* __restrict__ u1d,
    float* __restrict__ u2s, float* __restrict__ u2d) {
  int b = blockIdx.x, t = threadIdx.x;
  if (b < 64) {                       // W0t
    int idx = b * 256 + t; int c = idx >> 7, k = idx & 127;
    W0t[idx] = (unsigned short)bf16rne(W0[k * 128 + c]);
  } else if (b < 128) {               // W1t
    int idx = (b - 64) * 256 + t; int c = idx >> 7, k = idx & 127;
    W1t[idx] = (unsigned short)bf16rne(W1[k * 128 + c]);
  } else if (b < 144) {               // W2t (32 x 128)
    int idx = (b - 128) * 256 + t; int c = idx >> 7, k = idx & 127;
    W2t[idx] = (unsigned short)bf16rne(W2[k * 32 + c]);
  } else if (b == 144) {              // u0
    for (int it = 0; it < 4; ++it) {
      int idx = it * 256 + t;         // 0..1023
      int k = idx >> 3, rem = idx & 7, h = rem >> 1, sd = rem & 1;
      const float* av = sd ? a0d : a0s;
      float s = 0.f;
      for (int o = 0; o < 32; ++o) s += W0[k * 128 + h * 32 + o] * av[h * 32 + o];
      (sd ? u0d : u0s)[k * 4 + h] = s;
    }
  } else if (b == 145) {              // u1
    for (int it = 0; it < 4; ++it) {
      int idx = it * 256 + t;
      int k = idx >> 3, rem = idx & 7, h = rem >> 1, sd = rem & 1;
      const float* av = sd ? a1d : a1s;
      float s = 0.f;
      for (int o = 0; o < 32; ++o) s += W1[k * 128 + h * 32 + o] * av[h * 32 + o];
      (sd ? u1d : u1s)[k * 4 + h] = s;
    }
  } else {                            // u2 (256 outputs)
    int k = t >> 1, sd = t & 1;
    const float* av = sd ? a2d : a2s;
    float s = 0.f;
    for (int o = 0; o < 32; ++o) s += W2[k * 32 + o] * av[o];
    (sd ? u2d : u2s)[k] = s;
  }
}

// --------- xprep: x(f32) -> xbf(bf16) + es0/ed0 = x . u0 (one wave per node) -----

__global__ __launch_bounds__(256) void xprep_kernel(const float* __restrict__ x,
    unsigned* __restrict__ xbf, const float* __restrict__ u0s,
    const float* __restrict__ u0d, float* __restrict__ es, float* __restrict__ ed,
    int Nn) {
  int n = blockIdx.x * 4 + (threadIdx.x >> 6);
  if (n >= Nn) return;
  int l = threadIdx.x & 63;
  int c0 = 2 * l;
  float2 v = *(const float2*)&x[(size_t)n * 128 + c0];
  xbf[(size_t)n * 64 + l] = bf16rne(v.x) | (bf16rne(v.y) << 16);
  float ps[4], pd[4];
#pragma unroll
  for (int h = 0; h < 4; ++h) {
    ps[h] = v.x * u0s[c0 * 4 + h] + v.y * u0s[(c0 + 1) * 4 + h];
    pd[h] = v.x * u0d[c0 * 4 + h] + v.y * u0d[(c0 + 1) * 4 + h];
  }
#pragma unroll
  for (int h = 0; h < 4; ++h)
#pragma unroll
    for (int o = 32; o; o >>= 1) { ps[h] += __shfl_xor(ps[h], o); pd[h] += __shfl_xor(pd[h], o); }
  if (l == 0) {
#pragma unroll
    for (int h = 0; h < 4; ++h) { es[n * 4 + h] = ps[h]; ed[n * 4 + h] = pd[h]; }
  }
}

// --- MFMA GEMM: H(N x NC, fp8) = A(N x 128, bf16) @ W(128 x NC, bf16) -----------

template <int NC>
__global__ __launch_bounds__(256) void gemm_mfma(const unsigned short* __restrict__ Abf,
    const unsigned short* __restrict__ Wt, unsigned char* __restrict__ Hfp,
    int Nrows) {
  constexpr int NT = NC / 16;
  __shared__ unsigned short lw[NC][136];
  int tid = threadIdx.x;
  for (int idx = tid; idx < NC * 16; idx += 256) {
    int c = idx >> 4, k0 = (idx & 15) * 8;
    *(uint4*)&lw[c][k0] = *(const uint4*)&Wt[c * 128 + k0];
  }
  __syncthreads();
  int w = tid >> 6, l = tid & 63;
  int g = l >> 4, i = l & 15;
  int rbase = blockIdx.x * 64 + w * 16;
  int arow = rbase + i; arow = arow < Nrows ? arow : Nrows - 1;
  bf16x8 a[4];
#pragma unroll
  for (int kk = 0; kk < 4; ++kk)
    a[kk] = *(const bf16x8*)&Abf[(size_t)arow * 128 + kk * 32 + g * 8];
  f32x4 acc[NT];
#pragma unroll
  for (int t = 0; t < NT; ++t) acc[t] = (f32x4){0.f, 0.f, 0.f, 0.f};
#pragma unroll
  for (int kk = 0; kk < 4; ++kk) {
#pragma unroll
    for (int t = 0; t < NT; ++t) {
      bf16x8 b = *(const bf16x8*)&lw[t * 16 + i][kk * 32 + g * 8];
      acc[t] = __builtin_amdgcn_mfma_f32_16x16x32_bf16(a[kk], b, acc[t], 0, 0, 0);
    }
  }
  int crow0 = rbase + g * 4;
#pragma unroll
  for (int t = 0; t < NT; ++t)
#pragma unroll
    for (int r = 0; r < 4; ++r) {
      int row = crow0 + r;
      if (row < Nrows)
        Hfp[(size_t)row * NC + t * 16 + i] = fp8enc(acc[t][r]);
    }
}

// --- GAT aggregation (HH=128, 4 heads): 16 lanes/node, 4 nodes/wave, fp8 h ---
// R12-best loop; residual read as bf16 from the A-operand buffer (same slots
// this thread later overwrites -> race-free).

template <bool RES, int NEXT_NH>
__global__ __launch_bounds__(256) void gat_agg128(const uint2* __restrict__ hfp,
    const float* __restrict__ es, const float* __restrict__ ed,
    const int* __restrict__ offs, const int* __restrict__ csr,
    const float* __restrict__ bias, const float* __restrict__ gamma,
    const float* __restrict__ beta, const uint4* __restrict__ resid_bf,
    uint4* __restrict__ out_bf,
    const float* __restrict__ uns, const float* __restrict__ und,
    float* __restrict__ es_next, float* __restrict__ ed_next, int Nn) {
  constexpr int CHK = 8;
  int tid = threadIdx.x;
  int l = tid & 63;
  int q = l & 15;
  int n = blockIdx.x * 16 + (tid >> 6) * 4 + (l >> 4);
  if (n >= Nn) return;
  int hh = q >> 2;
  unsigned c0 = q * 8;
  float edn = ed[n * 4 + hh];
  float e0 = es[n * 4 + hh] + edn;   // self loop; softmax shift-invariant
  e0 = e0 > 0.f ? e0 : 0.2f * e0;
  float w0 = __expf(e0);
  float den = w0;
  float acc[8];
  {
    uint2 u = hfp[(unsigned)n * 16 + q];
    f32x2 p0 = __builtin_amdgcn_cvt_pk_f32_fp8(u.x, false);
    f32x2 p1 = __builtin_amdgcn_cvt_pk_f32_fp8(u.x, true);
    f32x2 p2 = __builtin_amdgcn_cvt_pk_f32_fp8(u.y, false);
    f32x2 p3 = __builtin_amdgcn_cvt_pk_f32_fp8(u.y, true);
    acc[0] = w0 * p0.x; acc[1] = w0 * p0.y;
    acc[2] = w0 * p1.x; acc[3] = w0 * p1.y;
    acc[4] = w0 * p2.x; acc[5] = w0 * p2.y;
    acc[6] = w0 * p3.x; acc[7] = w0 * p3.y;
  }
  int beg = offs[n], end = offs[n + 1];
  int s_cur[CHK];
#pragma unroll
  for (int j = 0; j < CHK; ++j) s_cur[j] = (beg + j < end) ? csr[beg + j] : n;
  for (int base = beg; base < end; base += CHK) {
    int s_nxt[CHK];
#pragma unroll
    for (int j = 0; j < CHK; ++j) {
      int idx = base + CHK + j;
      s_nxt[j] = (idx < end) ? csr[idx] : n;
    }
    int cnt = end - base;   // >=1
    uint2 hv[CHK];
#pragma unroll
    for (int j = 0; j < CHK; ++j) hv[j] = hfp[(unsigned)s_cur[j] * 16 + q];
    float w[CHK];
#pragma unroll
    for (int j = 0; j < CHK; ++j) {
      float e = es[s_cur[j] * 4 + hh] + edn;
      e = e > 0.f ? e : 0.2f * e;
      w[j] = (j < cnt) ? __expf(e) : 0.f;
    }
#pragma unroll
    for (int j = 0; j < CHK; ++j) {
      f32x2 p0 = __builtin_amdgcn_cvt_pk_f32_fp8(hv[j].x, false);
      f32x2 p1 = __builtin_amdgcn_cvt_pk_f32_fp8(hv[j].x, true);
      f32x2 p2 = __builtin_amdgcn_cvt_pk_f32_fp8(hv[j].y, false);
      f32x2 p3 = __builtin_amdgcn_cvt_pk_f32_fp8(hv[j].y, true);
      den += w[j];
      acc[0] += w[j] * p0.x; acc[1] += w[j] * p0.y;
      acc[2] += w[j] * p1.x; acc[3] += w[j] * p1.y;
      acc[4] += w[j] * p2.x; acc[5] += w[j] * p2.y;
      acc[6] += w[j] * p3.x; acc[7] += w[j] * p3.y;
    }
#pragma unroll
    for (int j = 0; j < CHK; ++j) s_cur[j] = s_nxt[j];
  }
  float inv = 1.0f / (den + 1e-16f);
  f32x4 bi0 = *(const f32x4*)&bias[c0],  bi1 = *(const f32x4*)&bias[c0 + 4];
  f32x4 ga0 = *(const f32x4*)&gamma[c0], ga1 = *(const f32x4*)&gamma[c0 + 4];
  f32x4 be0 = *(const f32x4*)&beta[c0],  be1 = *(const f32x4*)&beta[c0 + 4];
  float rv[8] = {0.f, 0.f, 0.f, 0.f, 0.f, 0.f, 0.f, 0.f};
  if (RES) {
    uint4 r4 = resid_bf[(unsigned)n * 16 + q];
    rv[0] = bf_lo(r4.x); rv[1] = bf_hi(r4.x);
    rv[2] = bf_lo(r4.y); rv[3] = bf_hi(r4.y);
    rv[4] = bf_lo(r4.z); rv[5] = bf_hi(r4.z);
    rv[6] = bf_lo(r4.w); rv[7] = bf_hi(r4.w);
  }
  float o[8];
#pragma unroll
  for (int k = 0; k < 8; ++k) {
    float bi = k < 4 ? bi0[k] : bi1[k - 4];
    float ga = k < 4 ? ga0[k] : ga1[k - 4];
    float be = k < 4 ? be0[k] : be1[k - 4];
    float v = acc[k] * inv + bi;
    if (RES) v += rv[k];
    v = ga * v * BN_INV + be;
    o[k] = v > 0.f ? v : __expf(v) - 1.f;
  }
  uint4 p;
  p.x = bf16rne(o[0]) | (bf16rne(o[1]) << 16);
  p.y = bf16rne(o[2]) | (bf16rne(o[3]) << 16);
  p.z = bf16rne(o[4]) | (bf16rne(o[5]) << 16);
  p.w = bf16rne(o[6]) | (bf16rne(o[7]) << 16);
  out_bf[(unsigned)n * 16 + q] = p;
  // next-layer attention coefficients: es_next = act . u  (16-lane reduce)
  if (NEXT_NH == 4) {
    const f32x4* uns4 = (const f32x4*)uns;
    const f32x4* und4 = (const f32x4*)und;
    f32x4 ps = (f32x4){0.f,0.f,0.f,0.f}, pd = ps;
#pragma unroll
    for (int k = 0; k < 8; ++k) {
      f32x4 us = uns4[c0 + k], ud = und4[c0 + k];
#pragma unroll
      for (int h = 0; h < 4; ++h) { ps[h] += o[k] * us[h]; pd[h] += o[k] * ud[h]; }
    }
#pragma unroll
    for (int h = 0; h < 4; ++h)
#pragma unroll
      for (int m = 1; m < 16; m <<= 1) {
        ps[h] += __shfl_xor(ps[h], m);
        pd[h] += __shfl_xor(pd[h], m);
      }
    if (q == 0) {
#pragma unroll
      for (int h = 0; h < 4; ++h) {
        es_next[n * 4 + h] = ps[h];
        ed_next[n * 4 + h] = pd[h];
      }
    }
  } else {
    float ps = 0.f, pd = 0.f;
#pragma unroll
    for (int k = 0; k < 8; ++k) { ps += o[k] * uns[c0 + k]; pd += o[k] * und[c0 + k]; }
#pragma unroll
    for (int m = 1; m < 16; m <<= 1) { ps += __shfl_xor(ps, m); pd += __shfl_xor(pd, m); }
    if (q == 0) { es_next[n] = ps; ed_next[n] = pd; }
  }
}

// --- layer-2 aggregation (H=1, O=32): 16 lanes/node (2 ch/lane), fp8 h ---

__global__ __launch_bounds__(256) void gat_agg32(const unsigned short* __restrict__ hfp,
    const float* __restrict__ es, const float* __restrict__ ed,
    const int* __restrict__ offs, const int* __restrict__ csr,
    const float* __restrict__ bias, float* __restrict__ h2, int Nn) {
  constexpr int CHK = 8;
  int tid = threadIdx.x;
  int l = tid & 63;
  int q = l & 15;
  int n = blockIdx.x * 16 + (tid >> 6) * 4 + (l >> 4);
  if (n >= Nn) return;
  float edn = ed[n];
  float e0 = es[n] + edn;
  e0 = e0 > 0.f ? e0 : 0.2f * e0;
  float w0 = __expf(e0);
  float den = w0;
  float accx, accy;
  {
    f32x2 p = __builtin_amdgcn_cvt_pk_f32_fp8((unsigned)hfp[(unsigned)n * 16 + q], false);
    accx = w0 * p.x; accy = w0 * p.y;
  }
  int beg = offs[n], end = offs[n + 1];
  int s_cur[CHK];
#pragma unroll
  for (int j = 0; j < CHK; ++j) s_cur[j] = (beg + j < end) ? csr[beg + j] : n;
  for (int base = beg; base < end; base += CHK) {
    int s_nxt[CHK];
#pragma unroll
    for (int j = 0; j < CHK; ++j) {
      int idx = base + CHK + j;
      s_nxt[j] = (idx < end) ? csr[idx] : n;
    }
    int cnt = end - base;
    unsigned short u[CHK];
#pragma unroll
    for (int j = 0; j < CHK; ++j) u[j] = hfp[(unsigned)s_cur[j] * 16 + q];
    float w[CHK];
#pragma unroll
    for (int j = 0; j < CHK; ++j) {
      float e = es[s_cur[j]] + edn;
      e = e > 0.f ? e : 0.2f * e;
      w[j] = (j < cnt) ? __expf(e) : 0.f;
    }
#pragma unroll
    for (int j = 0; j < CHK; ++j) {
      f32x2 p = __builtin_amdgcn_cvt_pk_f32_fp8((unsigned)u[j], false);
      den += w[j];
      accx += w[j] * p.x;
      accy += w[j] * p.y;
    }
#pragma unroll
    for (int j = 0; j < CHK; ++j) s_cur[j] = s_nxt[j];
  }
  float inv = 1.0f / (den + 1e-16f);
  float2 bi = *(const float2*)&bias[2 * q];
  float2 o;
  o.x = accx * inv + bi.x;
  o.y = accy * inv + bi.y;
  *(float2*)&h2[(size_t)n * 32 + 2 * q] = o;
}

// -------- head: mean-pool + conv1d x2 + MLP + log_softmax, 1024 thr/block -------

__global__ __launch_bounds__(1024) void head_kernel(const float* __restrict__ h2,
    const int* __restrict__ batch,
    const float* __restrict__ c0w, const float* __restrict__ c0b,
    const float* __restrict__ cg0, const float* __restrict__ cb0,
    const float* __restrict__ c1w, const float* __restrict__ c1b,
    const float* __restrict__ l1w, const float* __restrict__ l1b,
    const float* __restrict__ l2w, const float* __restrict__ l2b,
    float* __restrict__ out) {
  int b = blockIdx.x;
  int t = threadIdx.x;
  __shared__ float sums[32][32];
  __shared__ float pooled[32];
  __shared__ float z1[32][32];
  __shared__ float z2[16][32];
  __shared__ float emb[16];
  __shared__ float hfc[8];
  __shared__ float logits[10];

  int lo = 0, hi = NNODES;
  while (lo < hi) { int mid = (lo + hi) >> 1; if (batch[mid] < b) lo = mid + 1; else hi = mid; }
  int start = lo;
  lo = 0; hi = NNODES;
  while (lo < hi) { int mid = (lo + hi) >> 1; if (batch[mid] < b + 1) lo = mid + 1; else hi = mid; }
  int end = lo;

  {
    int ch = t & 31, g = t >> 5;     // g in 0..31
    float s = 0.f;
    int i = start + g;
    for (; i + 96 < end; i += 128) {
      float a0 = h2[(size_t)i * 32 + ch];
      float a1 = h2[(size_t)(i + 32) * 32 + ch];
      float a2 = h2[(size_t)(i + 64) * 32 + ch];
      float a3 = h2[(size_t)(i + 96) * 32 + ch];
      s += (a0 + a1) + (a2 + a3);
    }
    for (; i < end; i += 32) s += h2[(size_t)i * 32 + ch];
    sums[g][ch] = s;
  }
  __syncthreads();
  if (t < 32) {
    float s = 0.f;
#pragma unroll
    for (int g = 0; g < 32; ++g) s += sums[g][t];
    float cn = fmaxf((float)(end - start), 1.0f);
    pooled[t] = s / cn;
  }
  __syncthreads();
  // conv1: 1024 outputs, one per thread
  {
    int oc = t >> 5, tt = t & 31;
    float a = c0b[oc];
#pragma unroll
    for (int k = 0; k < 5; ++k) {
      int p = tt + k - 2;
      if (p >= 0 && p < 32) a += pooled[p] * c0w[oc * 5 + k];
    }
    a = cg0[oc] * a * BN_INV + cb0[oc];
    z1[oc][tt] = a > 0.f ? a : __expf(a) - 1.f;
  }
  __syncthreads();
  // conv2: 512 outputs on t<512
  if (t < 512) {
    int oc = t >> 5, tt = t & 31;
    float a = c1b[oc];
    for (int ic = 0; ic < 32; ++ic) {
      const float* wrow = &c1w[(oc * 32 + ic) * 5];
#pragma unroll
      for (int k = 0; k < 5; ++k) {
        int p = tt + k - 2;
        if (p >= 0 && p < 32) a += z1[ic][p] * wrow[k];
      }
    }
    z2[oc][tt] = a;
  }
  __syncthreads();
  if (t < 16) {
    float s = 0.f;
    for (int i = 0; i < 32; ++i) s += z2[t][i];
    s *= (1.0f / 32.0f);
    emb[t] = s;
    out[640 + b * 16 + t] = s;     // output 1: embed (64 x 16)
  }
  __syncthreads();
  if (t < 8) {
    float a = l1b[t];
    for (int i = 0; i < 16; ++i) a += emb[i] * l1w[i * 8 + t];
    hfc[t] = a > 0.f ? a : __expf(a) - 1.f;
  }
  __syncthreads();
  if (t < 10) {
    float a = l2b[t];
    for (int j = 0; j < 8; ++j) a += hfc[j] * l2w[j * 10 + t];
    logits[t] = a;
  }
  __syncthreads();
  if (t == 0) {
    float m = logits[0];
    for (int k = 1; k < 10; ++k) m = fmaxf(m, logits[k]);
    float s = 0.f;
    for (int k = 0; k < 10; ++k) s += __expf(logits[k] - m);
    float lse = m + logf(s);
    for (int k = 0; k < 10; ++k) out[b * 10 + k] = logits[k] - lse;  // output 0
  }
}

// ---------------- launch ----------------

extern "C" void kernel_launch(void* const* d_in, const int* in_sizes, int n_in,
                              void* d_out, int out_size, void* d_ws, size_t ws_size,
                              hipStream_t stream) {
  const float* x   = (const float*)d_in[0];
  const int* eidx  = (const int*)d_in[1];
  const int* esrc  = eidx;
  const int* edst  = eidx + NEDGES;
  const int* batch = (const int*)d_in[2];
  const float* W0  = (const float*)d_in[3];
  const float* a0s = (const float*)d_in[4];
  const float* a0d = (const float*)d_in[5];
  const float* b0  = (const float*)d_in[6];
  const float* W1  = (const float*)d_in[7];
  const float* a1s = (const float*)d_in[8];
  const float* a1d = (const float*)d_in[9];
  const float* b1  = (const float*)d_in[10];
  const float* W2  = (const float*)d_in[11];
  const float* a2s = (const float*)d_in[12];
  const float* a2d = (const float*)d_in[13];
  const float* b2  = (const float*)d_in[14];
  const float* g0  = (const float*)d_in[15];
  const float* be0 = (const float*)d_in[16];
  const float* g1  = (const float*)d_in[17];
  const float* be1 = (const float*)d_in[18];
  const float* c0w = (const float*)d_in[19];
  const float* c0b = (const float*)d_in[20];
  const float* cg0 = (const float*)d_in[21];
  const float* cb0 = (const float*)d_in[22];
  const float* c1w = (const float*)d_in[23];
  const float* c1b = (const float*)d_in[24];
  const float* l1w = (const float*)d_in[25];
  const float* l1b = (const float*)d_in[26];
  const float* l2w = (const float*)d_in[27];
  const float* l2b = (const float*)d_in[28];

  char* ws = (char*)d_ws;
  int*            deg    = (int*)(ws + 0);
  int*            cursor = (int*)(ws + 208448);
  int*            offs   = (int*)(ws + 408448);
  float*          esA    = (float*)(ws + 608512);
  float*          edA    = (float*)(ws + 1408512);
  float*          esB    = (float*)(ws + 2208512);
  float*          edB    = (float*)(ws + 3008512);
  int*            csr    = (int*)(ws + 3808512);
  unsigned*       Abf    = (unsigned*)(ws + 7008512);    // N x 64 uints (bf16 pairs)
  unsigned char*  hfp    = (unsigned char*)(ws + 19808512);  // N x 128 fp8 (l2: N x 32)
  float*          h2     = (float*)(ws + 32608512);      // N x 32 f32
  unsigned short* W0t    = (unsigned short*)(ws + 58208512);
  unsigned short* W1t    = (unsigned short*)(ws + 58241280);
  unsigned short* W2t    = (unsigned short*)(ws + 58274048);
  float*          u0s    = (float*)(ws + 58282240);
  float*          u0d    = (float*)(ws + 58284288);
  float*          u1s    = (float*)(ws + 58286336);
  float*          u1d    = (float*)(ws + 58288384);
  float*          u2s    = (float*)(ws + 58290432);
  float*          u2d    = (float*)(ws + 58290944);
  int*            sloc   = (int*)(ws + 58291456);        // 50000 i32 scan scratch
  int*            sbsum  = (int*)(ws + 58491456);        // 49 i32 block sums
  float*          out    = (float*)d_out;

  hipMemsetAsync(d_ws, 0, 200000, stream);   // deg = 0

  count_deg<<<1024, 256, 0, stream>>>(edst, deg, NEDGES / 4);
  scan_local<<<SCAN_NB, 1024, 0, stream>>>(deg, sloc, sbsum, NNODES);
  scan_finish<<<SCAN_NB, 1024, 0, stream>>>(sloc, sbsum, offs, cursor, NNODES, SCAN_NB);
  fill_csr<<<1024, 256, 0, stream>>>(esrc, edst, cursor, csr, NEDGES / 4);

  prep_kernel<<<147, 256, 0, stream>>>(W0, W1, W2, a0s, a0d, a1s, a1d, a2s, a2d,
                                       W0t, W1t, W2t, u0s, u0d, u1s, u1d, u2s, u2d);
  xprep_kernel<<<NNODES / 4, 256, 0, stream>>>(x, Abf, u0s, u0d, esA, edA, NNODES);

  const int ggrid = (NNODES + 63) / 64;
  const int agrid = (NNODES + 15) / 16;

  // --- layer 0 ---
  gemm_mfma<128><<<ggrid, 256, 0, stream>>>((const unsigned short*)Abf, W0t,
                                            hfp, NNODES);
  gat_agg128<false, 4><<<agrid, 256, 0, stream>>>(
      (const uint2*)hfp, esA, edA, offs, csr, b0, g0, be0, nullptr,
      (uint4*)Abf, u1s, u1d, esB, edB, NNODES);

  // --- layer 1 (residual from bf16 Abf; read-then-overwrite per-thread slot) ---
  gemm_mfma<128><<<ggrid, 256, 0, stream>>>((const unsigned short*)Abf, W1t,
                                            hfp, NNODES);
  gat_agg128<true, 1><<<agrid, 256, 0, stream>>>(
      (const uint2*)hfp, esB, edB, offs, csr, b1, g1, be1, (const uint4*)Abf,
      (uint4*)Abf, u2s, u2d, esA, edA, NNODES);

  // --- layer 2 (H=1, O=32) ---
  gemm_mfma<32><<<ggrid, 256, 0, stream>>>((const unsigned short*)Abf, W2t,
                                           hfp, NNODES);
  gat_agg32<<<agrid, 256, 0, stream>>>((const unsigned short*)hfp,
                                       esA, edA, offs, csr, b2, h2, NNODES);

  // --- head (pool fused, 1024 threads) ---
  head_kernel<<<64, 1024, 0, stream>>>(h2, batch, c0w, c0b, cg0, cb0,
                                       c1w, c1b, l1w, l1b, l2w, l2b, out);
}